// Round 9
// baseline (812.953 us; speedup 1.0000x reference)
//
#include <hip/hip_runtime.h>

// PointNet Set Abstraction (B=16, N=4096, S=1024, K=32, D=64, mlp 67->64->64->128)
// All buffers float32. Exact fp32 (RN, numpy op order) for all DECISIONS.
//
// R24: counter-spin sync. Budget fit across R18/R21/R22/R23 isolates a fixed
// ~800cyc/iter sync cost (s_barrier round trip at 1 block/CU); issue/ILP and
// wave-count are falsified levers (R21 null, R22/R23 negative). R20's LDS
// handshake failed for mechanism-specific reasons: s_sleep(1) quantization,
// divergent 4-word poll + __all ballot. This round replaces the in-loop
// barrier with: lane63 {relaxed key store -> RELEASE fetch_add on ONE LDS
// counter}; all lanes ACQUIRE-spin on that single broadcast word (no sleep,
// no divergence, uniform branch). Parity key buffers red[it&1] stay race-free
// (clobber of red[par] requires every wave's add for it+1, which follows its
// read of red[par]). After waves 4-7 exit each compute wave owns its SIMD ->
// spin cannot starve anyone. Everything else byte-identical to R21 (713us):
// 4 compute waves x 16pt, float4 pt, b128 key reads, consumer, grid 256x512.

typedef unsigned int   u32;
typedef unsigned long long u64;

#define NB 16
#define NP 4096
#define NS 1024
#define NK 32
#define NITEM (NB * NS / 2)   // 8192 pair items

#define DPP_UPD(v, ctrl) ((u32)__builtin_amdgcn_update_dpp((int)(v), (int)(v), (ctrl), 0xf, 0xf, false))
#define U64_STEP(v, ctrl) { \
  u32 _lo = DPP_UPD((u32)(v), ctrl); \
  u32 _hi = DPP_UPD((u32)((v) >> 32), ctrl); \
  u64 _o = (((u64)_hi) << 32) | _lo; \
  v = (v > _o) ? v : _o; }
#define WAVE_RED_U64MAX(v) do { U64_STEP(v,0x111); U64_STEP(v,0x112); U64_STEP(v,0x114); \
                                U64_STEP(v,0x118); U64_STEP(v,0x142); U64_STEP(v,0x143); } while (0)
#define UMAX_DPP(v, ctrl) { u32 _o = DPP_UPD(v, ctrl); v = (v > _o) ? v : _o; }
#define HALF_RED_UMAX32(v) do { UMAX_DPP(v,0x111); UMAX_DPP(v,0x112); UMAX_DPP(v,0x114); \
                                UMAX_DPP(v,0x118); UMAX_DPP(v,0x142); } while (0)

struct FpsS { float4 pt[NP]; u64 red[2][4]; u32 cnt; };
struct HalfS {
  float x0[64 * 67];
  u64 masks[2][64];
  int offs[2][64];
  int idx_ls[2][NK];
  float cent[8];
};
struct ConS { HalfS h[2]; float sAB[512]; int shi; };
union SMem { FpsS f; ConS c; };

__device__ __forceinline__ float dload_f(const float* p) {
  return __uint_as_float(__hip_atomic_load((const u32*)p, __ATOMIC_RELAXED, __HIP_MEMORY_SCOPE_AGENT));
}

__global__ void __launch_bounds__(512)
fused_kernel(const float* __restrict__ xyz, const float* __restrict__ pts,
             const float* __restrict__ W0, const float* __restrict__ b0, const float* __restrict__ g0,
             const float* __restrict__ be0, const float* __restrict__ m0, const float* __restrict__ v0,
             const float* __restrict__ W1, const float* __restrict__ b1, const float* __restrict__ g1,
             const float* __restrict__ be1, const float* __restrict__ m1, const float* __restrict__ v1,
             const float* __restrict__ W2, const float* __restrict__ b2, const float* __restrict__ g2,
             const float* __restrict__ be2, const float* __restrict__ m2, const float* __restrict__ v2,
             float* __restrict__ out0, float* __restrict__ out1,
             int* __restrict__ progress, int* __restrict__ ctr)
{
  __shared__ SMem sm;
  const int t = threadIdx.x;

  if (blockIdx.x < NB) {
    // ========== FPS producer: 4 compute waves, counter-spin sync ==========
    asm volatile("s_setprio 3");
    FpsS& S = sm.f;
    const int b = blockIdx.x;
    const int lane = t & 63, wv = t >> 6;
    const float* bx = xyz + (size_t)b * NP * 3;
    for (int i = t; i < NP; i += 512) {
      S.pt[i] = make_float4(bx[i * 3 + 0], bx[i * 3 + 1], bx[i * 3 + 2], 0.0f);
    }
    if (t == 0) S.cnt = 0;
    __syncthreads();              // all 8 waves participate; last barrier
    if (wv >= 4) return;          // waves 4-7 exit (R21-verified safe)

    // t in [0,256): point i = p*256 + t, p = 0..15
    float px[16], py[16], pz[16], md[16];
#pragma unroll
    for (int p = 0; p < 16; ++p) {
      float4 f4 = S.pt[p * 256 + t];
      px[p] = f4.x; py[p] = f4.y; pz[p] = f4.z;
      md[p] = 1e10f;
    }
    const u32 nt = ~(u32)t;
    float4 c4 = S.pt[0];
    float cx = c4.x, cy = c4.y, cz = c4.z;
    float hx = cx, hy = cy, hz = cz;   // lane 0's capture slot = centroid 0 (seed)

    for (int it = 1; it < NS; ++it) {
      u32 vb, ca;
      {
        float dx = __fsub_rn(px[0], cx);
        float dy = __fsub_rn(py[0], cy);
        float dz = __fsub_rn(pz[0], cz);
        float d  = __fadd_rn(__fadd_rn(__fmul_rn(dx, dx), __fmul_rn(dy, dy)), __fmul_rn(dz, dz));
        float m2 = fminf(md[0], d);
        md[0] = m2;
        vb = __float_as_uint(m2);
        ca = nt;
      }
#pragma unroll
      for (int p = 1; p < 16; ++p) {
        float dx = __fsub_rn(px[p], cx);
        float dy = __fsub_rn(py[p], cy);
        float dz = __fsub_rn(pz[p], cz);
        float d  = __fadd_rn(__fadd_rn(__fmul_rn(dx, dx), __fmul_rn(dy, dy)), __fmul_rn(dz, dz));
        float m2 = fminf(md[p], d);
        md[p] = m2;
        u32 mb = __float_as_uint(m2);
        bool gt = mb > vb;                      // strict > keeps first idx on ties
        vb = gt ? mb : vb;
        ca = gt ? (nt - (u32)(p * 256)) : ca;   // ~(p*256+t)
      }
      u64 key = (((u64)vb) << 32) | ca;
      WAVE_RED_U64MAX(key);
      const int par = it & 1;
      if (lane == 63) {
        __hip_atomic_store(&S.red[par][wv], key, __ATOMIC_RELAXED, __HIP_MEMORY_SCOPE_WORKGROUP);
        // RELEASE orders the key store before the counter bump
        __hip_atomic_fetch_add(&S.cnt, 1u, __ATOMIC_RELEASE, __HIP_MEMORY_SCOPE_WORKGROUP);
      }
      // uniform broadcast spin: all 4 waves published iteration `it`?
      const u32 tgt = 4u * (u32)it;
      for (;;) {
        u32 c = __hip_atomic_load(&S.cnt, __ATOMIC_ACQUIRE, __HIP_MEMORY_SCOPE_WORKGROUP);
        if (c >= tgt) break;
      }
      const ulonglong2* rp2 = (const ulonglong2*)S.red[par];
      ulonglong2 kk0 = rp2[0], kk1 = rp2[1];
      u64 m01 = (kk0.x > kk0.y) ? kk0.x : kk0.y;
      u64 m23 = (kk1.x > kk1.y) ? kk1.x : kk1.y;
      u64 bk = (m01 > m23) ? m01 : m23;
      const int idx = (int)(~(u32)bk);
      float4 cc = S.pt[idx];
      cx = cc.x; cy = cc.y; cz = cc.z;
      if (wv == 0) {
        // lane (it&15) captures this iteration's centroid
        bool cap = (lane == (it & 15));
        hx = cap ? cx : hx;
        hy = cap ? cy : hy;
        hz = cap ? cz : hz;
        if ((it & 15) == 15) {
          if (lane < 16) {                       // burst cents (it-15)..it, 192B coalesced
            float* o = out0 + ((size_t)b * NS + (it - 15) + lane) * 3;
            o[0] = hx; o[1] = hy; o[2] = hz;
          }
          if (lane == 0)                         // release fences the burst agent-wide
            __hip_atomic_store(&progress[b * 16], it + 1, __ATOMIC_RELEASE, __HIP_MEMORY_SCOPE_AGENT);
        }
      }
    }
    return;
  }

  // ================= consumer (byte-identical to R18/R21) =================
  ConS& C = sm.c;
  const int half = t >> 8;
  const int u = t & 255;
  const int lane = t & 63;
  const int hw = u >> 6;
  HalfS& H = C.h[half];
  const float R2 = (float)(0.2 * 0.2);

  if (t < 256) {
    const float *gp, *bep, *mp, *vp, *bpp; int c, base, bcoff;
    if (t < 64)       { c = t;       gp = g0; bep = be0; mp = m0; vp = v0; bpp = b0; base = 0;   bcoff = 64;  }
    else if (t < 128) { c = t - 64;  gp = g1; bep = be1; mp = m1; vp = v1; bpp = b1; base = 128; bcoff = 64;  }
    else              { c = t - 128; gp = g2; bep = be2; mp = m2; vp = v2; bpp = b2; base = 256; bcoff = 128; }
    float a = gp[c] / sqrtf(vp[c] + 1e-5f);
    C.sAB[base + c] = a;
    C.sAB[base + bcoff + c] = (bpp[c] - mp[c]) * a + bep[c];
  }
  __syncthreads();

  for (;;) {
    if (t == 0) C.shi = atomicAdd(ctr, 2);
    __syncthreads();
    const int i0 = C.shi;
    if (i0 >= NITEM) break;
    const int item = i0 + half;
    const bool active = item < NITEM;
    const int b = item & 15, pr = item >> 4, s0 = pr * 2;

    if (u == 0 && active) {
      const int need = s0 + 2;
      while (__hip_atomic_load(&progress[b * 16], __ATOMIC_ACQUIRE, __HIP_MEMORY_SCOPE_AGENT) < need)
        __builtin_amdgcn_s_sleep(32);
      const float* cp = out0 + ((size_t)b * NS + s0) * 3;
#pragma unroll
      for (int i2 = 0; i2 < 6; ++i2) H.cent[i2] = dload_f(cp + i2);
    }
    __syncthreads();
    const float c0x = H.cent[0], c0y = H.cent[1], c0z = H.cent[2];
    const float c1x = H.cent[3], c1y = H.cent[4], c1z = H.cent[5];
    const float* bx = xyz + (size_t)b * NP * 3;

    if (active) {
      for (int c = 0; c < 16; ++c) {
        int ch = hw * 16 + c;
        int i = ch * 64 + lane;
        float X = bx[i * 3 + 0], Y = bx[i * 3 + 1], Z = bx[i * 3 + 2];
        float dx0 = __fsub_rn(c0x, X), dy0 = __fsub_rn(c0y, Y), dz0 = __fsub_rn(c0z, Z);
        float d20 = __fadd_rn(__fadd_rn(__fmul_rn(dx0, dx0), __fmul_rn(dy0, dy0)), __fmul_rn(dz0, dz0));
        u64 mA = __ballot(d20 < R2);
        float dx1 = __fsub_rn(c1x, X), dy1 = __fsub_rn(c1y, Y), dz1 = __fsub_rn(c1z, Z);
        float d21 = __fadd_rn(__fadd_rn(__fmul_rn(dx1, dx1), __fmul_rn(dy1, dy1)), __fmul_rn(dz1, dz1));
        u64 mB = __ballot(d21 < R2);
        if (lane == 0) { H.masks[0][ch] = mA; H.masks[1][ch] = mB; }
      }
      if (u < 64) H.idx_ls[u >> 5][u & 31] = -1;
    }
    __syncthreads();
    if (active && (hw & 1) == 0) {
      int cent = hw >> 1;
      int cnt = __popcll(H.masks[cent][lane]);
      int inc = cnt;
#pragma unroll
      for (int off = 1; off < 64; off <<= 1) {
        int n = __shfl_up(inc, off);
        if (lane >= off) inc += n;
      }
      H.offs[cent][lane] = inc - cnt;
    }
    __syncthreads();
    if (active) {
      for (int c = 0; c < 16; ++c) {
        int ch = hw * 16 + c;
#pragma unroll
        for (int cent = 0; cent < 2; ++cent) {
          int base = H.offs[cent][ch];
          if (base >= NK) continue;
          u64 m = H.masks[cent][ch];
          if ((m >> lane) & 1ull) {
            int slot = base + __popcll(m & ((1ull << lane) - 1ull));
            if (slot < NK) H.idx_ls[cent][slot] = ch * 64 + lane;
          }
        }
      }
    }
    __syncthreads();
    if (active) {
      int cent = u >> 7, tt = u & 127;
      int row = tt >> 2, q = tt & 3;
      int id = H.idx_ls[cent][row];
      int prow = (id < 0) ? (NP - 1) : id;          // torch -1 wrap
      const float4* p4 = (const float4*)(pts + ((size_t)b * NP + prow) * 64 + q * 16);
      float4 va = p4[0], vb = p4[1], vc = p4[2], vd = p4[3];
      float* dst = &H.x0[(cent * 32 + row) * 67 + 3 + q * 16];
      dst[0]  = va.x; dst[1]  = va.y; dst[2]  = va.z; dst[3]  = va.w;
      dst[4]  = vb.x; dst[5]  = vb.y; dst[6]  = vb.z; dst[7]  = vb.w;
      dst[8]  = vc.x; dst[9]  = vc.y; dst[10] = vc.z; dst[11] = vc.w;
      dst[12] = vd.x; dst[13] = vd.y; dst[14] = vd.z; dst[15] = vd.w;
      if (u < 64) {
        int c2 = u >> 5, slot = u & 31;
        int id2 = H.idx_ls[c2][slot];
        float ax = c2 ? c1x : c0x, ay = c2 ? c1y : c0y, az = c2 ? c1z : c0z;
        float gx, gy, gz;
        if (id2 >= 0) {
          gx = __fsub_rn(bx[id2 * 3 + 0], ax);
          gy = __fsub_rn(bx[id2 * 3 + 1], ay);
          gz = __fsub_rn(bx[id2 * 3 + 2], az);
        } else {
          gx = 0.0f - ax; gy = 0.0f - ay; gz = 0.0f - az;
        }
        float* d2p = &H.x0[(c2 * 32 + slot) * 67];
        d2p[0] = gx; d2p[1] = gy; d2p[2] = gz;
      }
    }
    __syncthreads();

    const int j0 = __builtin_amdgcn_readfirstlane(hw * 16);
    // --- layer 1: 67 -> 64 (in-place)
    {
      float acc[16];
#pragma unroll
      for (int i = 0; i < 16; ++i) acc[i] = 0.0f;
      if (active) {
        const float* xr = &H.x0[lane * 67];
#pragma unroll 2
        for (int c = 0; c < 67; ++c) {
          float xv = xr[c];
          const float4* wr = (const float4*)(W0 + c * 64 + j0);
          float4 wa = wr[0], wb = wr[1], wc = wr[2], wd = wr[3];
          acc[0]  = fmaf(xv, wa.x, acc[0]);  acc[1]  = fmaf(xv, wa.y, acc[1]);
          acc[2]  = fmaf(xv, wa.z, acc[2]);  acc[3]  = fmaf(xv, wa.w, acc[3]);
          acc[4]  = fmaf(xv, wb.x, acc[4]);  acc[5]  = fmaf(xv, wb.y, acc[5]);
          acc[6]  = fmaf(xv, wb.z, acc[6]);  acc[7]  = fmaf(xv, wb.w, acc[7]);
          acc[8]  = fmaf(xv, wc.x, acc[8]);  acc[9]  = fmaf(xv, wc.y, acc[9]);
          acc[10] = fmaf(xv, wc.z, acc[10]); acc[11] = fmaf(xv, wc.w, acc[11]);
          acc[12] = fmaf(xv, wd.x, acc[12]); acc[13] = fmaf(xv, wd.y, acc[13]);
          acc[14] = fmaf(xv, wd.z, acc[14]); acc[15] = fmaf(xv, wd.w, acc[15]);
        }
      }
      __syncthreads();
      if (active) {
#pragma unroll
        for (int i = 0; i < 16; ++i) {
          float y = fmaf(acc[i], C.sAB[j0 + i], C.sAB[64 + j0 + i]);
          H.x0[lane * 67 + j0 + i] = fmaxf(y, 0.0f);
        }
      }
    }
    __syncthreads();
    // --- layer 2: 64 -> 64 (in-place)
    {
      float acc[16];
#pragma unroll
      for (int i = 0; i < 16; ++i) acc[i] = 0.0f;
      if (active) {
        const float* xr = &H.x0[lane * 67];
#pragma unroll 2
        for (int c = 0; c < 64; ++c) {
          float xv = xr[c];
          const float4* wr = (const float4*)(W1 + c * 64 + j0);
          float4 wa = wr[0], wb = wr[1], wc = wr[2], wd = wr[3];
          acc[0]  = fmaf(xv, wa.x, acc[0]);  acc[1]  = fmaf(xv, wa.y, acc[1]);
          acc[2]  = fmaf(xv, wa.z, acc[2]);  acc[3]  = fmaf(xv, wa.w, acc[3]);
          acc[4]  = fmaf(xv, wb.x, acc[4]);  acc[5]  = fmaf(xv, wb.y, acc[5]);
          acc[6]  = fmaf(xv, wb.z, acc[6]);  acc[7]  = fmaf(xv, wb.w, acc[7]);
          acc[8]  = fmaf(xv, wc.x, acc[8]);  acc[9]  = fmaf(xv, wc.y, acc[9]);
          acc[10] = fmaf(xv, wc.z, acc[10]); acc[11] = fmaf(xv, wc.w, acc[11]);
          acc[12] = fmaf(xv, wd.x, acc[12]); acc[13] = fmaf(xv, wd.y, acc[13]);
          acc[14] = fmaf(xv, wd.z, acc[14]); acc[15] = fmaf(xv, wd.w, acc[15]);
        }
      }
      __syncthreads();
      if (active) {
#pragma unroll
        for (int i = 0; i < 16; ++i) {
          float y = fmaf(acc[i], C.sAB[128 + j0 + i], C.sAB[192 + j0 + i]);
          H.x0[lane * 67 + j0 + i] = fmaxf(y, 0.0f);
        }
      }
    }
    __syncthreads();
    // --- layer 3: 64 -> 128 + max over 32 rows per centroid
    if (active) {
      const int j3 = __builtin_amdgcn_readfirstlane(hw * 32);
      float acc[32];
#pragma unroll
      for (int i = 0; i < 32; ++i) acc[i] = 0.0f;
      const float* xr = &H.x0[lane * 67];
      for (int c = 0; c < 64; ++c) {
        float xv = xr[c];
        const float4* wr = (const float4*)(W2 + c * 128 + j3);
#pragma unroll
        for (int q = 0; q < 8; ++q) {
          float4 wq = wr[q];
          acc[q * 4 + 0] = fmaf(xv, wq.x, acc[q * 4 + 0]);
          acc[q * 4 + 1] = fmaf(xv, wq.y, acc[q * 4 + 1]);
          acc[q * 4 + 2] = fmaf(xv, wq.z, acc[q * 4 + 2]);
          acc[q * 4 + 3] = fmaf(xv, wq.w, acc[q * 4 + 3]);
        }
      }
#pragma unroll
      for (int i = 0; i < 32; ++i) {
        float y = fmaf(acc[i], C.sAB[256 + j3 + i], C.sAB[384 + j3 + i]);
        u32 mb = __float_as_uint(fmaxf(y, 0.0f));
        HALF_RED_UMAX32(mb);
        acc[i] = __uint_as_float(mb);
      }
      if (lane == 31 || lane == 63) {
        int cent = lane >> 5;
        float4* op = (float4*)(out1 + ((size_t)b * NS + s0 + cent) * 128 + j3);
#pragma unroll
        for (int q = 0; q < 8; ++q)
          op[q] = make_float4(acc[q * 4 + 0], acc[q * 4 + 1], acc[q * 4 + 2], acc[q * 4 + 3]);
      }
    }
  }
}

// ---------------------------------------------------------------- launcher
extern "C" void kernel_launch(void* const* d_in, const int* in_sizes, int n_in,
                              void* d_out, int out_size, void* d_ws, size_t ws_size,
                              hipStream_t stream) {
  const float* xyz = (const float*)d_in[0];
  const float* pts = (const float*)d_in[1];
  const float* W0 = (const float*)d_in[2];  const float* b0 = (const float*)d_in[3];
  const float* g0 = (const float*)d_in[4];  const float* be0 = (const float*)d_in[5];
  const float* m0 = (const float*)d_in[6];  const float* v0 = (const float*)d_in[7];
  const float* W1 = (const float*)d_in[8];  const float* b1 = (const float*)d_in[9];
  const float* g1 = (const float*)d_in[10]; const float* be1 = (const float*)d_in[11];
  const float* m1 = (const float*)d_in[12]; const float* v1 = (const float*)d_in[13];
  const float* W2 = (const float*)d_in[14]; const float* b2 = (const float*)d_in[15];
  const float* g2 = (const float*)d_in[16]; const float* be2 = (const float*)d_in[17];
  const float* m2 = (const float*)d_in[18]; const float* v2 = (const float*)d_in[19];

  float* out0 = (float*)d_out;           // new_xyz    (B,S,3)
  float* out1 = out0 + NB * NS * 3;      // new_points (B,S,128)
  int* prog = (int*)d_ws;                // progress[b] at int b*16 (64B-strided lines)
  int* ctr  = (int*)d_ws + 320;          // work counter, own line

  hipMemsetAsync(d_ws, 0, 2048, stream);

  // Grid 256 x 512 (R13/R18 config): producers = blocks 0-15 dispatched first,
  // 1 block/CU, co-residency safe, consumer = 240 blocks x 2 item-units.
  fused_kernel<<<256, 512, 0, stream>>>(
      xyz, pts,
      W0, b0, g0, be0, m0, v0,
      W1, b1, g1, be1, m1, v1,
      W2, b2, g2, be2, m2, v2,
      out0, out1, prog, ctr);
}

// Round 10
// 770.852 us; speedup vs baseline: 1.0546x; 1.0546x over previous
//
#include <hip/hip_runtime.h>

// PointNet Set Abstraction (B=16, N=4096, S=1024, K=32, D=64, mlp 67->64->64->128)
// All buffers float32. Exact fp32 (RN, numpy op order) for all DECISIONS.
//
// R25: R21 (best, 713us counters) + publish off the barrier drain.
// Sync-mechanism ranking measured: s_barrier 713 < counter-spin 765 (R24) <
// handshake 828 (R20) -> common-cost dominated; keep s_barrier. Remaining
// identified slack: compiler emits s_waitcnt vmcnt(0) before s_barrier, so
// wave 0's 49 global stores (burst+progress, every 16th iter) stall ALL
// waves ~500-900cyc at the next barrier. Fix:
//  (1) in-loop barrier = asm {s_waitcnt lgkmcnt(0); s_barrier} -- LDS key
//      visibility fully ordered, global stores no longer gate the barrier.
//  (2) progress RELEASE store deferred one iteration ((it&15)==0, value=it):
//      burst stores are then ~1700cyc old -> release's implicit vmcnt(0) is
//      free. Final progress=NS published after the loop.
// Everything else (4 compute waves x 16pt, waves 4-7 exit, float4 pt, b128
// key reads, consumer, grid 256x512): byte-identical to R21.

typedef unsigned int   u32;
typedef unsigned long long u64;

#define NB 16
#define NP 4096
#define NS 1024
#define NK 32
#define NITEM (NB * NS / 2)   // 8192 pair items

#define DPP_UPD(v, ctrl) ((u32)__builtin_amdgcn_update_dpp((int)(v), (int)(v), (ctrl), 0xf, 0xf, false))
#define U64_STEP(v, ctrl) { \
  u32 _lo = DPP_UPD((u32)(v), ctrl); \
  u32 _hi = DPP_UPD((u32)((v) >> 32), ctrl); \
  u64 _o = (((u64)_hi) << 32) | _lo; \
  v = (v > _o) ? v : _o; }
#define WAVE_RED_U64MAX(v) do { U64_STEP(v,0x111); U64_STEP(v,0x112); U64_STEP(v,0x114); \
                                U64_STEP(v,0x118); U64_STEP(v,0x142); U64_STEP(v,0x143); } while (0)
#define UMAX_DPP(v, ctrl) { u32 _o = DPP_UPD(v, ctrl); v = (v > _o) ? v : _o; }
#define HALF_RED_UMAX32(v) do { UMAX_DPP(v,0x111); UMAX_DPP(v,0x112); UMAX_DPP(v,0x114); \
                                UMAX_DPP(v,0x118); UMAX_DPP(v,0x142); } while (0)

struct FpsS { float4 pt[NP]; u64 red[2][4]; };
struct HalfS {
  float x0[64 * 67];
  u64 masks[2][64];
  int offs[2][64];
  int idx_ls[2][NK];
  float cent[8];
};
struct ConS { HalfS h[2]; float sAB[512]; int shi; };
union SMem { FpsS f; ConS c; };

__device__ __forceinline__ float dload_f(const float* p) {
  return __uint_as_float(__hip_atomic_load((const u32*)p, __ATOMIC_RELAXED, __HIP_MEMORY_SCOPE_AGENT));
}

__global__ void __launch_bounds__(512)
fused_kernel(const float* __restrict__ xyz, const float* __restrict__ pts,
             const float* __restrict__ W0, const float* __restrict__ b0, const float* __restrict__ g0,
             const float* __restrict__ be0, const float* __restrict__ m0, const float* __restrict__ v0,
             const float* __restrict__ W1, const float* __restrict__ b1, const float* __restrict__ g1,
             const float* __restrict__ be1, const float* __restrict__ m1, const float* __restrict__ v1,
             const float* __restrict__ W2, const float* __restrict__ b2, const float* __restrict__ g2,
             const float* __restrict__ be2, const float* __restrict__ m2, const float* __restrict__ v2,
             float* __restrict__ out0, float* __restrict__ out1,
             int* __restrict__ progress, int* __restrict__ ctr)
{
  __shared__ SMem sm;
  const int t = threadIdx.x;

  if (blockIdx.x < NB) {
    // ========== FPS producer: 4 compute waves, lgkm-only barrier ==========
    asm volatile("s_setprio 3");
    FpsS& S = sm.f;
    const int b = blockIdx.x;
    const int lane = t & 63, wv = t >> 6;
    const float* bx = xyz + (size_t)b * NP * 3;
    for (int i = t; i < NP; i += 512) {
      S.pt[i] = make_float4(bx[i * 3 + 0], bx[i * 3 + 1], bx[i * 3 + 2], 0.0f);
    }
    __syncthreads();              // all 8 waves participate
    if (wv >= 4) return;          // waves 4-7 exit (R21-verified safe)

    // t in [0,256): point i = p*256 + t, p = 0..15
    float px[16], py[16], pz[16], md[16];
#pragma unroll
    for (int p = 0; p < 16; ++p) {
      float4 f4 = S.pt[p * 256 + t];
      px[p] = f4.x; py[p] = f4.y; pz[p] = f4.z;
      md[p] = 1e10f;
    }
    const u32 nt = ~(u32)t;
    float4 c4 = S.pt[0];
    float cx = c4.x, cy = c4.y, cz = c4.z;
    float hx = cx, hy = cy, hz = cz;   // lane 0's capture slot = centroid 0 (seed)

    for (int it = 1; it < NS; ++it) {
      u32 vb, ca;
      {
        float dx = __fsub_rn(px[0], cx);
        float dy = __fsub_rn(py[0], cy);
        float dz = __fsub_rn(pz[0], cz);
        float d  = __fadd_rn(__fadd_rn(__fmul_rn(dx, dx), __fmul_rn(dy, dy)), __fmul_rn(dz, dz));
        float m2 = fminf(md[0], d);
        md[0] = m2;
        vb = __float_as_uint(m2);
        ca = nt;
      }
#pragma unroll
      for (int p = 1; p < 16; ++p) {
        float dx = __fsub_rn(px[p], cx);
        float dy = __fsub_rn(py[p], cy);
        float dz = __fsub_rn(pz[p], cz);
        float d  = __fadd_rn(__fadd_rn(__fmul_rn(dx, dx), __fmul_rn(dy, dy)), __fmul_rn(dz, dz));
        float m2 = fminf(md[p], d);
        md[p] = m2;
        u32 mb = __float_as_uint(m2);
        bool gt = mb > vb;                      // strict > keeps first idx on ties
        vb = gt ? mb : vb;
        ca = gt ? (nt - (u32)(p * 256)) : ca;   // ~(p*256+t)
      }
      u64 key = (((u64)vb) << 32) | ca;
      WAVE_RED_U64MAX(key);
      const int par = it & 1;
      if (lane == 63) S.red[par][wv] = key;
      // lgkm-only barrier: LDS key write ordered; global stores NOT drained
      asm volatile("s_waitcnt lgkmcnt(0)\n\ts_barrier" ::: "memory");
      const ulonglong2* rp2 = (const ulonglong2*)S.red[par];
      ulonglong2 kk0 = rp2[0], kk1 = rp2[1];
      u64 m01 = (kk0.x > kk0.y) ? kk0.x : kk0.y;
      u64 m23 = (kk1.x > kk1.y) ? kk1.x : kk1.y;
      u64 bk = (m01 > m23) ? m01 : m23;
      const int idx = (int)(~(u32)bk);
      float4 cc = S.pt[idx];
      cx = cc.x; cy = cc.y; cz = cc.z;
      if (wv == 0) {
        // deferred publish for the burst issued last iteration: stores are
        // ~1700cyc old -> release's implicit vmcnt(0) drain is free
        if ((it & 15) == 0 && lane == 0)
          __hip_atomic_store(&progress[b * 16], it, __ATOMIC_RELEASE, __HIP_MEMORY_SCOPE_AGENT);
        // lane (it&15) captures this iteration's centroid
        bool cap = (lane == (it & 15));
        hx = cap ? cx : hx;
        hy = cap ? cy : hy;
        hz = cap ? cz : hz;
        if ((it & 15) == 15) {
          if (lane < 16) {                       // burst cents (it-15)..it, plain stores
            float* o = out0 + ((size_t)b * NS + (it - 15) + lane) * 3;
            o[0] = hx; o[1] = hy; o[2] = hz;
          }
        }
      }
    }
    // final publish: orders the last burst (vmcnt drain at loop exit, off the
    // iteration critical path)
    if (wv == 0 && lane == 0)
      __hip_atomic_store(&progress[b * 16], NS, __ATOMIC_RELEASE, __HIP_MEMORY_SCOPE_AGENT);
    return;
  }

  // ================= consumer (byte-identical to R18/R21) =================
  ConS& C = sm.c;
  const int half = t >> 8;
  const int u = t & 255;
  const int lane = t & 63;
  const int hw = u >> 6;
  HalfS& H = C.h[half];
  const float R2 = (float)(0.2 * 0.2);

  if (t < 256) {
    const float *gp, *bep, *mp, *vp, *bpp; int c, base, bcoff;
    if (t < 64)       { c = t;       gp = g0; bep = be0; mp = m0; vp = v0; bpp = b0; base = 0;   bcoff = 64;  }
    else if (t < 128) { c = t - 64;  gp = g1; bep = be1; mp = m1; vp = v1; bpp = b1; base = 128; bcoff = 64;  }
    else              { c = t - 128; gp = g2; bep = be2; mp = m2; vp = v2; bpp = b2; base = 256; bcoff = 128; }
    float a = gp[c] / sqrtf(vp[c] + 1e-5f);
    C.sAB[base + c] = a;
    C.sAB[base + bcoff + c] = (bpp[c] - mp[c]) * a + bep[c];
  }
  __syncthreads();

  for (;;) {
    if (t == 0) C.shi = atomicAdd(ctr, 2);
    __syncthreads();
    const int i0 = C.shi;
    if (i0 >= NITEM) break;
    const int item = i0 + half;
    const bool active = item < NITEM;
    const int b = item & 15, pr = item >> 4, s0 = pr * 2;

    if (u == 0 && active) {
      const int need = s0 + 2;
      while (__hip_atomic_load(&progress[b * 16], __ATOMIC_ACQUIRE, __HIP_MEMORY_SCOPE_AGENT) < need)
        __builtin_amdgcn_s_sleep(32);
      const float* cp = out0 + ((size_t)b * NS + s0) * 3;
#pragma unroll
      for (int i2 = 0; i2 < 6; ++i2) H.cent[i2] = dload_f(cp + i2);
    }
    __syncthreads();
    const float c0x = H.cent[0], c0y = H.cent[1], c0z = H.cent[2];
    const float c1x = H.cent[3], c1y = H.cent[4], c1z = H.cent[5];
    const float* bx = xyz + (size_t)b * NP * 3;

    if (active) {
      for (int c = 0; c < 16; ++c) {
        int ch = hw * 16 + c;
        int i = ch * 64 + lane;
        float X = bx[i * 3 + 0], Y = bx[i * 3 + 1], Z = bx[i * 3 + 2];
        float dx0 = __fsub_rn(c0x, X), dy0 = __fsub_rn(c0y, Y), dz0 = __fsub_rn(c0z, Z);
        float d20 = __fadd_rn(__fadd_rn(__fmul_rn(dx0, dx0), __fmul_rn(dy0, dy0)), __fmul_rn(dz0, dz0));
        u64 mA = __ballot(d20 < R2);
        float dx1 = __fsub_rn(c1x, X), dy1 = __fsub_rn(c1y, Y), dz1 = __fsub_rn(c1z, Z);
        float d21 = __fadd_rn(__fadd_rn(__fmul_rn(dx1, dx1), __fmul_rn(dy1, dy1)), __fmul_rn(dz1, dz1));
        u64 mB = __ballot(d21 < R2);
        if (lane == 0) { H.masks[0][ch] = mA; H.masks[1][ch] = mB; }
      }
      if (u < 64) H.idx_ls[u >> 5][u & 31] = -1;
    }
    __syncthreads();
    if (active && (hw & 1) == 0) {
      int cent = hw >> 1;
      int cnt = __popcll(H.masks[cent][lane]);
      int inc = cnt;
#pragma unroll
      for (int off = 1; off < 64; off <<= 1) {
        int n = __shfl_up(inc, off);
        if (lane >= off) inc += n;
      }
      H.offs[cent][lane] = inc - cnt;
    }
    __syncthreads();
    if (active) {
      for (int c = 0; c < 16; ++c) {
        int ch = hw * 16 + c;
#pragma unroll
        for (int cent = 0; cent < 2; ++cent) {
          int base = H.offs[cent][ch];
          if (base >= NK) continue;
          u64 m = H.masks[cent][ch];
          if ((m >> lane) & 1ull) {
            int slot = base + __popcll(m & ((1ull << lane) - 1ull));
            if (slot < NK) H.idx_ls[cent][slot] = ch * 64 + lane;
          }
        }
      }
    }
    __syncthreads();
    if (active) {
      int cent = u >> 7, tt = u & 127;
      int row = tt >> 2, q = tt & 3;
      int id = H.idx_ls[cent][row];
      int prow = (id < 0) ? (NP - 1) : id;          // torch -1 wrap
      const float4* p4 = (const float4*)(pts + ((size_t)b * NP + prow) * 64 + q * 16);
      float4 va = p4[0], vb = p4[1], vc = p4[2], vd = p4[3];
      float* dst = &H.x0[(cent * 32 + row) * 67 + 3 + q * 16];
      dst[0]  = va.x; dst[1]  = va.y; dst[2]  = va.z; dst[3]  = va.w;
      dst[4]  = vb.x; dst[5]  = vb.y; dst[6]  = vb.z; dst[7]  = vb.w;
      dst[8]  = vc.x; dst[9]  = vc.y; dst[10] = vc.z; dst[11] = vc.w;
      dst[12] = vd.x; dst[13] = vd.y; dst[14] = vd.z; dst[15] = vd.w;
      if (u < 64) {
        int c2 = u >> 5, slot = u & 31;
        int id2 = H.idx_ls[c2][slot];
        float ax = c2 ? c1x : c0x, ay = c2 ? c1y : c0y, az = c2 ? c1z : c0z;
        float gx, gy, gz;
        if (id2 >= 0) {
          gx = __fsub_rn(bx[id2 * 3 + 0], ax);
          gy = __fsub_rn(bx[id2 * 3 + 1], ay);
          gz = __fsub_rn(bx[id2 * 3 + 2], az);
        } else {
          gx = 0.0f - ax; gy = 0.0f - ay; gz = 0.0f - az;
        }
        float* d2p = &H.x0[(c2 * 32 + slot) * 67];
        d2p[0] = gx; d2p[1] = gy; d2p[2] = gz;
      }
    }
    __syncthreads();

    const int j0 = __builtin_amdgcn_readfirstlane(hw * 16);
    // --- layer 1: 67 -> 64 (in-place)
    {
      float acc[16];
#pragma unroll
      for (int i = 0; i < 16; ++i) acc[i] = 0.0f;
      if (active) {
        const float* xr = &H.x0[lane * 67];
#pragma unroll 2
        for (int c = 0; c < 67; ++c) {
          float xv = xr[c];
          const float4* wr = (const float4*)(W0 + c * 64 + j0);
          float4 wa = wr[0], wb = wr[1], wc = wr[2], wd = wr[3];
          acc[0]  = fmaf(xv, wa.x, acc[0]);  acc[1]  = fmaf(xv, wa.y, acc[1]);
          acc[2]  = fmaf(xv, wa.z, acc[2]);  acc[3]  = fmaf(xv, wa.w, acc[3]);
          acc[4]  = fmaf(xv, wb.x, acc[4]);  acc[5]  = fmaf(xv, wb.y, acc[5]);
          acc[6]  = fmaf(xv, wb.z, acc[6]);  acc[7]  = fmaf(xv, wb.w, acc[7]);
          acc[8]  = fmaf(xv, wc.x, acc[8]);  acc[9]  = fmaf(xv, wc.y, acc[9]);
          acc[10] = fmaf(xv, wc.z, acc[10]); acc[11] = fmaf(xv, wc.w, acc[11]);
          acc[12] = fmaf(xv, wd.x, acc[12]); acc[13] = fmaf(xv, wd.y, acc[13]);
          acc[14] = fmaf(xv, wd.z, acc[14]); acc[15] = fmaf(xv, wd.w, acc[15]);
        }
      }
      __syncthreads();
      if (active) {
#pragma unroll
        for (int i = 0; i < 16; ++i) {
          float y = fmaf(acc[i], C.sAB[j0 + i], C.sAB[64 + j0 + i]);
          H.x0[lane * 67 + j0 + i] = fmaxf(y, 0.0f);
        }
      }
    }
    __syncthreads();
    // --- layer 2: 64 -> 64 (in-place)
    {
      float acc[16];
#pragma unroll
      for (int i = 0; i < 16; ++i) acc[i] = 0.0f;
      if (active) {
        const float* xr = &H.x0[lane * 67];
#pragma unroll 2
        for (int c = 0; c < 64; ++c) {
          float xv = xr[c];
          const float4* wr = (const float4*)(W1 + c * 64 + j0);
          float4 wa = wr[0], wb = wr[1], wc = wr[2], wd = wr[3];
          acc[0]  = fmaf(xv, wa.x, acc[0]);  acc[1]  = fmaf(xv, wa.y, acc[1]);
          acc[2]  = fmaf(xv, wa.z, acc[2]);  acc[3]  = fmaf(xv, wa.w, acc[3]);
          acc[4]  = fmaf(xv, wb.x, acc[4]);  acc[5]  = fmaf(xv, wb.y, acc[5]);
          acc[6]  = fmaf(xv, wb.z, acc[6]);  acc[7]  = fmaf(xv, wb.w, acc[7]);
          acc[8]  = fmaf(xv, wc.x, acc[8]);  acc[9]  = fmaf(xv, wc.y, acc[9]);
          acc[10] = fmaf(xv, wc.z, acc[10]); acc[11] = fmaf(xv, wc.w, acc[11]);
          acc[12] = fmaf(xv, wd.x, acc[12]); acc[13] = fmaf(xv, wd.y, acc[13]);
          acc[14] = fmaf(xv, wd.z, acc[14]); acc[15] = fmaf(xv, wd.w, acc[15]);
        }
      }
      __syncthreads();
      if (active) {
#pragma unroll
        for (int i = 0; i < 16; ++i) {
          float y = fmaf(acc[i], C.sAB[128 + j0 + i], C.sAB[192 + j0 + i]);
          H.x0[lane * 67 + j0 + i] = fmaxf(y, 0.0f);
        }
      }
    }
    __syncthreads();
    // --- layer 3: 64 -> 128 + max over 32 rows per centroid
    if (active) {
      const int j3 = __builtin_amdgcn_readfirstlane(hw * 32);
      float acc[32];
#pragma unroll
      for (int i = 0; i < 32; ++i) acc[i] = 0.0f;
      const float* xr = &H.x0[lane * 67];
      for (int c = 0; c < 64; ++c) {
        float xv = xr[c];
        const float4* wr = (const float4*)(W2 + c * 128 + j3);
#pragma unroll
        for (int q = 0; q < 8; ++q) {
          float4 wq = wr[q];
          acc[q * 4 + 0] = fmaf(xv, wq.x, acc[q * 4 + 0]);
          acc[q * 4 + 1] = fmaf(xv, wq.y, acc[q * 4 + 1]);
          acc[q * 4 + 2] = fmaf(xv, wq.z, acc[q * 4 + 2]);
          acc[q * 4 + 3] = fmaf(xv, wq.w, acc[q * 4 + 3]);
        }
      }
#pragma unroll
      for (int i = 0; i < 32; ++i) {
        float y = fmaf(acc[i], C.sAB[256 + j3 + i], C.sAB[384 + j3 + i]);
        u32 mb = __float_as_uint(fmaxf(y, 0.0f));
        HALF_RED_UMAX32(mb);
        acc[i] = __uint_as_float(mb);
      }
      if (lane == 31 || lane == 63) {
        int cent = lane >> 5;
        float4* op = (float4*)(out1 + ((size_t)b * NS + s0 + cent) * 128 + j3);
#pragma unroll
        for (int q = 0; q < 8; ++q)
          op[q] = make_float4(acc[q * 4 + 0], acc[q * 4 + 1], acc[q * 4 + 2], acc[q * 4 + 3]);
      }
    }
  }
}

// ---------------------------------------------------------------- launcher
extern "C" void kernel_launch(void* const* d_in, const int* in_sizes, int n_in,
                              void* d_out, int out_size, void* d_ws, size_t ws_size,
                              hipStream_t stream) {
  const float* xyz = (const float*)d_in[0];
  const float* pts = (const float*)d_in[1];
  const float* W0 = (const float*)d_in[2];  const float* b0 = (const float*)d_in[3];
  const float* g0 = (const float*)d_in[4];  const float* be0 = (const float*)d_in[5];
  const float* m0 = (const float*)d_in[6];  const float* v0 = (const float*)d_in[7];
  const float* W1 = (const float*)d_in[8];  const float* b1 = (const float*)d_in[9];
  const float* g1 = (const float*)d_in[10]; const float* be1 = (const float*)d_in[11];
  const float* m1 = (const float*)d_in[12]; const float* v1 = (const float*)d_in[13];
  const float* W2 = (const float*)d_in[14]; const float* b2 = (const float*)d_in[15];
  const float* g2 = (const float*)d_in[16]; const float* be2 = (const float*)d_in[17];
  const float* m2 = (const float*)d_in[18]; const float* v2 = (const float*)d_in[19];

  float* out0 = (float*)d_out;           // new_xyz    (B,S,3)
  float* out1 = out0 + NB * NS * 3;      // new_points (B,S,128)
  int* prog = (int*)d_ws;                // progress[b] at int b*16 (64B-strided lines)
  int* ctr  = (int*)d_ws + 320;          // work counter, own line

  hipMemsetAsync(d_ws, 0, 2048, stream);

  // Grid 256 x 512 (R13/R18 config): producers = blocks 0-15 dispatched first,
  // 1 block/CU, co-residency safe, consumer = 240 blocks x 2 item-units.
  fused_kernel<<<256, 512, 0, stream>>>(
      xyz, pts,
      W0, b0, g0, be0, m0, v0,
      W1, b1, g1, be1, m1, v1,
      W2, b2, g2, be2, m2, v2,
      out0, out1, prog, ctr);
}

// Round 11
// 755.712 us; speedup vs baseline: 1.0757x; 1.0200x over previous
//
#include <hip/hip_runtime.h>

// PointNet Set Abstraction (B=16, N=4096, S=1024, K=32, D=64, mlp 67->64->64->128)
// All buffers float32. Exact fp32 (RN, numpy op order) for all DECISIONS.
//
// R26: packed-fp32 distance phase on the R21 base (best plain-barrier config).
// Sync mechanisms fully mapped (s_barrier 713 < lgkm-asm 736 < spin 765 <
// handshake 828): exchange cost is mechanism-independent. Remaining lever:
// fp32 issue width. gfx90a+ has v_pk_{add,mul}_f32 (2x fp32/inst). The dist
// phase's explicit __f*_rn intrinsics block SLP -> ~256 scalar-issue cycles
// on the serial critical path. This round packs dist+md-update as
// ext_vector_type(2) under `#pragma clang fp contract(off)`:
//  - vector sub/mul/add = per-element IEEE RN, bit-identical to scalar
//  - contract(off) forbids FMA fusion (decision exactness preserved)
//  - argmax scan stays scalar, ascending pp order, strict > (ties identical)
// R25's lgkm-barrier + deferred publish REVERTED (736 vs 713: negative).
// Everything else byte-identical R21: 4 compute waves x 16pt (waves 4-7 exit
// after staging), plain __syncthreads in-loop, b128 key reads, burst publish,
// consumer, grid 256x512 (1 block/CU, producers = blocks 0-15).
// Tripwire: WRITE_SIZE ~8.5MB flat; jump = spills = revert.

typedef unsigned int   u32;
typedef unsigned long long u64;
typedef float f32x2 __attribute__((ext_vector_type(2)));

#define NB 16
#define NP 4096
#define NS 1024
#define NK 32
#define NITEM (NB * NS / 2)   // 8192 pair items

#define DPP_UPD(v, ctrl) ((u32)__builtin_amdgcn_update_dpp((int)(v), (int)(v), (ctrl), 0xf, 0xf, false))
#define U64_STEP(v, ctrl) { \
  u32 _lo = DPP_UPD((u32)(v), ctrl); \
  u32 _hi = DPP_UPD((u32)((v) >> 32), ctrl); \
  u64 _o = (((u64)_hi) << 32) | _lo; \
  v = (v > _o) ? v : _o; }
#define WAVE_RED_U64MAX(v) do { U64_STEP(v,0x111); U64_STEP(v,0x112); U64_STEP(v,0x114); \
                                U64_STEP(v,0x118); U64_STEP(v,0x142); U64_STEP(v,0x143); } while (0)
#define UMAX_DPP(v, ctrl) { u32 _o = DPP_UPD(v, ctrl); v = (v > _o) ? v : _o; }
#define HALF_RED_UMAX32(v) do { UMAX_DPP(v,0x111); UMAX_DPP(v,0x112); UMAX_DPP(v,0x114); \
                                UMAX_DPP(v,0x118); UMAX_DPP(v,0x142); } while (0)

struct FpsS { float4 pt[NP]; u64 red[2][4]; };
struct HalfS {
  float x0[64 * 67];
  u64 masks[2][64];
  int offs[2][64];
  int idx_ls[2][NK];
  float cent[8];
};
struct ConS { HalfS h[2]; float sAB[512]; int shi; };
union SMem { FpsS f; ConS c; };

__device__ __forceinline__ float dload_f(const float* p) {
  return __uint_as_float(__hip_atomic_load((const u32*)p, __ATOMIC_RELAXED, __HIP_MEMORY_SCOPE_AGENT));
}

__global__ void __launch_bounds__(512)
fused_kernel(const float* __restrict__ xyz, const float* __restrict__ pts,
             const float* __restrict__ W0, const float* __restrict__ b0, const float* __restrict__ g0,
             const float* __restrict__ be0, const float* __restrict__ m0, const float* __restrict__ v0,
             const float* __restrict__ W1, const float* __restrict__ b1, const float* __restrict__ g1,
             const float* __restrict__ be1, const float* __restrict__ m1, const float* __restrict__ v1,
             const float* __restrict__ W2, const float* __restrict__ b2, const float* __restrict__ g2,
             const float* __restrict__ be2, const float* __restrict__ m2, const float* __restrict__ v2,
             float* __restrict__ out0, float* __restrict__ out1,
             int* __restrict__ progress, int* __restrict__ ctr)
{
  __shared__ SMem sm;
  const int t = threadIdx.x;

  if (blockIdx.x < NB) {
    // ====== FPS producer: 4 compute waves x 16 pts, packed-f32 dist phase ======
    asm volatile("s_setprio 3");
    FpsS& S = sm.f;
    const int b = blockIdx.x;
    const int lane = t & 63, wv = t >> 6;
    const float* bx = xyz + (size_t)b * NP * 3;
    for (int i = t; i < NP; i += 512) {
      S.pt[i] = make_float4(bx[i * 3 + 0], bx[i * 3 + 1], bx[i * 3 + 2], 0.0f);
    }
    __syncthreads();              // all 8 waves participate
    if (wv >= 4) return;          // waves 4-7 exit (R21-verified safe);
                                  // loop below syncs the 4 live waves

    // t in [0,256): pair p packs points pp=2p (x-slot) and pp=2p+1 (y-slot),
    // global point index = pp*256 + t
    f32x2 px2[8], py2[8], pz2[8], md2[8];
#pragma unroll
    for (int p = 0; p < 8; ++p) {
      float4 a4 = S.pt[(2 * p) * 256 + t];
      float4 b4 = S.pt[(2 * p + 1) * 256 + t];
      px2[p].x = a4.x; px2[p].y = b4.x;
      py2[p].x = a4.y; py2[p].y = b4.y;
      pz2[p].x = a4.z; pz2[p].y = b4.z;
      md2[p].x = 1e10f; md2[p].y = 1e10f;
    }
    const u32 nt = ~(u32)t;
    float4 c4 = S.pt[0];
    float cx = c4.x, cy = c4.y, cz = c4.z;
    float hx = cx, hy = cy, hz = cz;   // lane 0's capture slot = centroid 0 (seed)

    for (int it = 1; it < NS; ++it) {
      // --- packed distance + md update (exact: per-element RN, no contraction)
      {
#pragma clang fp contract(off)
        f32x2 vcx; vcx.x = cx; vcx.y = cx;
        f32x2 vcy; vcy.x = cy; vcy.y = cy;
        f32x2 vcz; vcz.x = cz; vcz.y = cz;
#pragma unroll
        for (int p = 0; p < 8; ++p) {
          f32x2 dx = px2[p] - vcx;
          f32x2 dy = py2[p] - vcy;
          f32x2 dz = pz2[p] - vcz;
          f32x2 xx = dx * dx;
          f32x2 yy = dy * dy;
          f32x2 zz = dz * dz;
          f32x2 ss = (xx + yy) + zz;
          md2[p].x = fminf(md2[p].x, ss.x);
          md2[p].y = fminf(md2[p].y, ss.y);
        }
      }
      // --- scalar argmax scan, ascending pp, strict > (first index wins ties)
      u32 vb = __float_as_uint(md2[0].x);
      u32 ca = nt;                               // pp = 0
      {
        u32 m1 = __float_as_uint(md2[0].y);      // pp = 1
        bool g1 = m1 > vb;
        vb = g1 ? m1 : vb;
        ca = g1 ? (nt - (u32)256) : ca;
      }
#pragma unroll
      for (int p = 1; p < 8; ++p) {
        u32 m0 = __float_as_uint(md2[p].x);      // pp = 2p
        bool g0 = m0 > vb;
        vb = g0 ? m0 : vb;
        ca = g0 ? (nt - (u32)(2 * p * 256)) : ca;
        u32 m1 = __float_as_uint(md2[p].y);      // pp = 2p+1
        bool g1 = m1 > vb;
        vb = g1 ? m1 : vb;
        ca = g1 ? (nt - (u32)((2 * p + 1) * 256)) : ca;
      }
      u64 key = (((u64)vb) << 32) | ca;
      WAVE_RED_U64MAX(key);
      const int par = it & 1;
      if (lane == 63) S.red[par][wv] = key;
      __syncthreads();            // 4-wave barrier
      const ulonglong2* rp2 = (const ulonglong2*)S.red[par];
      ulonglong2 kk0 = rp2[0], kk1 = rp2[1];
      u64 m01 = (kk0.x > kk0.y) ? kk0.x : kk0.y;
      u64 m23 = (kk1.x > kk1.y) ? kk1.x : kk1.y;
      u64 bk = (m01 > m23) ? m01 : m23;
      const int idx = (int)(~(u32)bk);
      float4 cc = S.pt[idx];
      cx = cc.x; cy = cc.y; cz = cc.z;
      if (wv == 0) {
        // lane (it&15) captures this iteration's centroid
        bool cap = (lane == (it & 15));
        hx = cap ? cx : hx;
        hy = cap ? cy : hy;
        hz = cap ? cz : hz;
        if ((it & 15) == 15) {
          if (lane < 16) {                       // burst cents (it-15)..it, 192B coalesced
            float* o = out0 + ((size_t)b * NS + (it - 15) + lane) * 3;
            o[0] = hx; o[1] = hy; o[2] = hz;
          }
          if (lane == 0)                         // release fences the burst agent-wide
            __hip_atomic_store(&progress[b * 16], it + 1, __ATOMIC_RELEASE, __HIP_MEMORY_SCOPE_AGENT);
        }
      }
    }
    return;
  }

  // ================= consumer (byte-identical to R18/R21) =================
  ConS& C = sm.c;
  const int half = t >> 8;
  const int u = t & 255;
  const int lane = t & 63;
  const int hw = u >> 6;
  HalfS& H = C.h[half];
  const float R2 = (float)(0.2 * 0.2);

  if (t < 256) {
    const float *gp, *bep, *mp, *vp, *bpp; int c, base, bcoff;
    if (t < 64)       { c = t;       gp = g0; bep = be0; mp = m0; vp = v0; bpp = b0; base = 0;   bcoff = 64;  }
    else if (t < 128) { c = t - 64;  gp = g1; bep = be1; mp = m1; vp = v1; bpp = b1; base = 128; bcoff = 64;  }
    else              { c = t - 128; gp = g2; bep = be2; mp = m2; vp = v2; bpp = b2; base = 256; bcoff = 128; }
    float a = gp[c] / sqrtf(vp[c] + 1e-5f);
    C.sAB[base + c] = a;
    C.sAB[base + bcoff + c] = (bpp[c] - mp[c]) * a + bep[c];
  }
  __syncthreads();

  for (;;) {
    if (t == 0) C.shi = atomicAdd(ctr, 2);
    __syncthreads();
    const int i0 = C.shi;
    if (i0 >= NITEM) break;
    const int item = i0 + half;
    const bool active = item < NITEM;
    const int b = item & 15, pr = item >> 4, s0 = pr * 2;

    if (u == 0 && active) {
      const int need = s0 + 2;
      while (__hip_atomic_load(&progress[b * 16], __ATOMIC_ACQUIRE, __HIP_MEMORY_SCOPE_AGENT) < need)
        __builtin_amdgcn_s_sleep(32);
      const float* cp = out0 + ((size_t)b * NS + s0) * 3;
#pragma unroll
      for (int i2 = 0; i2 < 6; ++i2) H.cent[i2] = dload_f(cp + i2);
    }
    __syncthreads();
    const float c0x = H.cent[0], c0y = H.cent[1], c0z = H.cent[2];
    const float c1x = H.cent[3], c1y = H.cent[4], c1z = H.cent[5];
    const float* bx = xyz + (size_t)b * NP * 3;

    if (active) {
      for (int c = 0; c < 16; ++c) {
        int ch = hw * 16 + c;
        int i = ch * 64 + lane;
        float X = bx[i * 3 + 0], Y = bx[i * 3 + 1], Z = bx[i * 3 + 2];
        float dx0 = __fsub_rn(c0x, X), dy0 = __fsub_rn(c0y, Y), dz0 = __fsub_rn(c0z, Z);
        float d20 = __fadd_rn(__fadd_rn(__fmul_rn(dx0, dx0), __fmul_rn(dy0, dy0)), __fmul_rn(dz0, dz0));
        u64 mA = __ballot(d20 < R2);
        float dx1 = __fsub_rn(c1x, X), dy1 = __fsub_rn(c1y, Y), dz1 = __fsub_rn(c1z, Z);
        float d21 = __fadd_rn(__fadd_rn(__fmul_rn(dx1, dx1), __fmul_rn(dy1, dy1)), __fmul_rn(dz1, dz1));
        u64 mB = __ballot(d21 < R2);
        if (lane == 0) { H.masks[0][ch] = mA; H.masks[1][ch] = mB; }
      }
      if (u < 64) H.idx_ls[u >> 5][u & 31] = -1;
    }
    __syncthreads();
    if (active && (hw & 1) == 0) {
      int cent = hw >> 1;
      int cnt = __popcll(H.masks[cent][lane]);
      int inc = cnt;
#pragma unroll
      for (int off = 1; off < 64; off <<= 1) {
        int n = __shfl_up(inc, off);
        if (lane >= off) inc += n;
      }
      H.offs[cent][lane] = inc - cnt;
    }
    __syncthreads();
    if (active) {
      for (int c = 0; c < 16; ++c) {
        int ch = hw * 16 + c;
#pragma unroll
        for (int cent = 0; cent < 2; ++cent) {
          int base = H.offs[cent][ch];
          if (base >= NK) continue;
          u64 m = H.masks[cent][ch];
          if ((m >> lane) & 1ull) {
            int slot = base + __popcll(m & ((1ull << lane) - 1ull));
            if (slot < NK) H.idx_ls[cent][slot] = ch * 64 + lane;
          }
        }
      }
    }
    __syncthreads();
    if (active) {
      int cent = u >> 7, tt = u & 127;
      int row = tt >> 2, q = tt & 3;
      int id = H.idx_ls[cent][row];
      int prow = (id < 0) ? (NP - 1) : id;          // torch -1 wrap
      const float4* p4 = (const float4*)(pts + ((size_t)b * NP + prow) * 64 + q * 16);
      float4 va = p4[0], vb = p4[1], vc = p4[2], vd = p4[3];
      float* dst = &H.x0[(cent * 32 + row) * 67 + 3 + q * 16];
      dst[0]  = va.x; dst[1]  = va.y; dst[2]  = va.z; dst[3]  = va.w;
      dst[4]  = vb.x; dst[5]  = vb.y; dst[6]  = vb.z; dst[7]  = vb.w;
      dst[8]  = vc.x; dst[9]  = vc.y; dst[10] = vc.z; dst[11] = vc.w;
      dst[12] = vd.x; dst[13] = vd.y; dst[14] = vd.z; dst[15] = vd.w;
      if (u < 64) {
        int c2 = u >> 5, slot = u & 31;
        int id2 = H.idx_ls[c2][slot];
        float ax = c2 ? c1x : c0x, ay = c2 ? c1y : c0y, az = c2 ? c1z : c0z;
        float gx, gy, gz;
        if (id2 >= 0) {
          gx = __fsub_rn(bx[id2 * 3 + 0], ax);
          gy = __fsub_rn(bx[id2 * 3 + 1], ay);
          gz = __fsub_rn(bx[id2 * 3 + 2], az);
        } else {
          gx = 0.0f - ax; gy = 0.0f - ay; gz = 0.0f - az;
        }
        float* d2p = &H.x0[(c2 * 32 + slot) * 67];
        d2p[0] = gx; d2p[1] = gy; d2p[2] = gz;
      }
    }
    __syncthreads();

    const int j0 = __builtin_amdgcn_readfirstlane(hw * 16);
    // --- layer 1: 67 -> 64 (in-place)
    {
      float acc[16];
#pragma unroll
      for (int i = 0; i < 16; ++i) acc[i] = 0.0f;
      if (active) {
        const float* xr = &H.x0[lane * 67];
#pragma unroll 2
        for (int c = 0; c < 67; ++c) {
          float xv = xr[c];
          const float4* wr = (const float4*)(W0 + c * 64 + j0);
          float4 wa = wr[0], wb = wr[1], wc = wr[2], wd = wr[3];
          acc[0]  = fmaf(xv, wa.x, acc[0]);  acc[1]  = fmaf(xv, wa.y, acc[1]);
          acc[2]  = fmaf(xv, wa.z, acc[2]);  acc[3]  = fmaf(xv, wa.w, acc[3]);
          acc[4]  = fmaf(xv, wb.x, acc[4]);  acc[5]  = fmaf(xv, wb.y, acc[5]);
          acc[6]  = fmaf(xv, wb.z, acc[6]);  acc[7]  = fmaf(xv, wb.w, acc[7]);
          acc[8]  = fmaf(xv, wc.x, acc[8]);  acc[9]  = fmaf(xv, wc.y, acc[9]);
          acc[10] = fmaf(xv, wc.z, acc[10]); acc[11] = fmaf(xv, wc.w, acc[11]);
          acc[12] = fmaf(xv, wd.x, acc[12]); acc[13] = fmaf(xv, wd.y, acc[13]);
          acc[14] = fmaf(xv, wd.z, acc[14]); acc[15] = fmaf(xv, wd.w, acc[15]);
        }
      }
      __syncthreads();
      if (active) {
#pragma unroll
        for (int i = 0; i < 16; ++i) {
          float y = fmaf(acc[i], C.sAB[j0 + i], C.sAB[64 + j0 + i]);
          H.x0[lane * 67 + j0 + i] = fmaxf(y, 0.0f);
        }
      }
    }
    __syncthreads();
    // --- layer 2: 64 -> 64 (in-place)
    {
      float acc[16];
#pragma unroll
      for (int i = 0; i < 16; ++i) acc[i] = 0.0f;
      if (active) {
        const float* xr = &H.x0[lane * 67];
#pragma unroll 2
        for (int c = 0; c < 64; ++c) {
          float xv = xr[c];
          const float4* wr = (const float4*)(W1 + c * 64 + j0);
          float4 wa = wr[0], wb = wr[1], wc = wr[2], wd = wr[3];
          acc[0]  = fmaf(xv, wa.x, acc[0]);  acc[1]  = fmaf(xv, wa.y, acc[1]);
          acc[2]  = fmaf(xv, wa.z, acc[2]);  acc[3]  = fmaf(xv, wa.w, acc[3]);
          acc[4]  = fmaf(xv, wb.x, acc[4]);  acc[5]  = fmaf(xv, wb.y, acc[5]);
          acc[6]  = fmaf(xv, wb.z, acc[6]);  acc[7]  = fmaf(xv, wb.w, acc[7]);
          acc[8]  = fmaf(xv, wc.x, acc[8]);  acc[9]  = fmaf(xv, wc.y, acc[9]);
          acc[10] = fmaf(xv, wc.z, acc[10]); acc[11] = fmaf(xv, wc.w, acc[11]);
          acc[12] = fmaf(xv, wd.x, acc[12]); acc[13] = fmaf(xv, wd.y, acc[13]);
          acc[14] = fmaf(xv, wd.z, acc[14]); acc[15] = fmaf(xv, wd.w, acc[15]);
        }
      }
      __syncthreads();
      if (active) {
#pragma unroll
        for (int i = 0; i < 16; ++i) {
          float y = fmaf(acc[i], C.sAB[128 + j0 + i], C.sAB[192 + j0 + i]);
          H.x0[lane * 67 + j0 + i] = fmaxf(y, 0.0f);
        }
      }
    }
    __syncthreads();
    // --- layer 3: 64 -> 128 + max over 32 rows per centroid
    if (active) {
      const int j3 = __builtin_amdgcn_readfirstlane(hw * 32);
      float acc[32];
#pragma unroll
      for (int i = 0; i < 32; ++i) acc[i] = 0.0f;
      const float* xr = &H.x0[lane * 67];
      for (int c = 0; c < 64; ++c) {
        float xv = xr[c];
        const float4* wr = (const float4*)(W2 + c * 128 + j3);
#pragma unroll
        for (int q = 0; q < 8; ++q) {
          float4 wq = wr[q];
          acc[q * 4 + 0] = fmaf(xv, wq.x, acc[q * 4 + 0]);
          acc[q * 4 + 1] = fmaf(xv, wq.y, acc[q * 4 + 1]);
          acc[q * 4 + 2] = fmaf(xv, wq.z, acc[q * 4 + 2]);
          acc[q * 4 + 3] = fmaf(xv, wq.w, acc[q * 4 + 3]);
        }
      }
#pragma unroll
      for (int i = 0; i < 32; ++i) {
        float y = fmaf(acc[i], C.sAB[256 + j3 + i], C.sAB[384 + j3 + i]);
        u32 mb = __float_as_uint(fmaxf(y, 0.0f));
        HALF_RED_UMAX32(mb);
        acc[i] = __uint_as_float(mb);
      }
      if (lane == 31 || lane == 63) {
        int cent = lane >> 5;
        float4* op = (float4*)(out1 + ((size_t)b * NS + s0 + cent) * 128 + j3);
#pragma unroll
        for (int q = 0; q < 8; ++q)
          op[q] = make_float4(acc[q * 4 + 0], acc[q * 4 + 1], acc[q * 4 + 2], acc[q * 4 + 3]);
      }
    }
  }
}

// ---------------------------------------------------------------- launcher
extern "C" void kernel_launch(void* const* d_in, const int* in_sizes, int n_in,
                              void* d_out, int out_size, void* d_ws, size_t ws_size,
                              hipStream_t stream) {
  const float* xyz = (const float*)d_in[0];
  const float* pts = (const float*)d_in[1];
  const float* W0 = (const float*)d_in[2];  const float* b0 = (const float*)d_in[3];
  const float* g0 = (const float*)d_in[4];  const float* be0 = (const float*)d_in[5];
  const float* m0 = (const float*)d_in[6];  const float* v0 = (const float*)d_in[7];
  const float* W1 = (const float*)d_in[8];  const float* b1 = (const float*)d_in[9];
  const float* g1 = (const float*)d_in[10]; const float* be1 = (const float*)d_in[11];
  const float* m1 = (const float*)d_in[12]; const float* v1 = (const float*)d_in[13];
  const float* W2 = (const float*)d_in[14]; const float* b2 = (const float*)d_in[15];
  const float* g2 = (const float*)d_in[16]; const float* be2 = (const float*)d_in[17];
  const float* m2 = (const float*)d_in[18]; const float* v2 = (const float*)d_in[19];

  float* out0 = (float*)d_out;           // new_xyz    (B,S,3)
  float* out1 = out0 + NB * NS * 3;      // new_points (B,S,128)
  int* prog = (int*)d_ws;                // progress[b] at int b*16 (64B-strided lines)
  int* ctr  = (int*)d_ws + 320;          // work counter, own line

  hipMemsetAsync(d_ws, 0, 2048, stream);

  // Grid 256 x 512 (R13/R18 config): producers = blocks 0-15 dispatched first,
  // 1 block/CU, co-residency safe, consumer = 240 blocks x 2 item-units.
  fused_kernel<<<256, 512, 0, stream>>>(
      xyz, pts,
      W0, b0, g0, be0, m0, v0,
      W1, b1, g1, be1, m1, v1,
      W2, b2, g2, be2, m2, v2,
      out0, out1, prog, ctr);
}